// Round 10
// baseline (526.000 us; speedup 1.0000x reference)
//
#include <hip/hip_runtime.h>

// SNNLinear, exact-trajectory i8-digit MFMA. Round 10 = R8 GEMM (verbatim)
// with the scan FUSED via per-bn completion counters (release/acquire with
// device-scope atomics + __threadfence; no cooperative launch):
//   - each GEMM block: stores tile -> __syncthreads (vmcnt drain) ->
//     tid0 __threadfence (L2 writeback) -> atomicAdd(colcnt[bn]).
//   - the 50th finisher for a bn acquires (__threadfence) and scans that
//     bn's 2048 chains (8 chains/thread, all f64, 2-slot prefetch).
//   - prepass (merged, proven) + zeroes the 32 counters. 2 dispatches.
// Math proven R3-R8 (bit-identical): Wq=round(W*2^36), 5 balanced base-256
// i8 digit planes; mfma_i32_16x16x64_i8 exact; i64 Horner -> f64 du ->
// f32 hi (ss region) + f16 lo*2^12 (ws). Scan in f64.
// Outputs: ss[100,64,1024] | mem_out[64,1024] | hat_s[64,1024]
// ws: [0,6.55M) A8 ; [6.55M,11.8M) Bt ; [11.8M,24.9M) Lo ; [25.0M) colcnt[32]

typedef __attribute__((ext_vector_type(4))) int int4v;

#define T_STEPS 100
#define BO 65536
#define K_DIM 1024
#define A8_OFF 0
#define BT_OFF 6553600
#define LO_OFF 11796480
#define CNT_OFF 25000000

// ---- merged prepass + counter zeroing ----
__global__ __launch_bounds__(256)
void prepass(const float* __restrict__ S, const float* __restrict__ W,
             signed char* __restrict__ A8, signed char* __restrict__ Bt,
             int* __restrict__ colcnt) {
    const int bid = blockIdx.x;
    if (bid < 1600) {
        // spikes f32 -> i8, A-fragment order
        const int id = bid * 256 + threadIdx.x;          // 0..409599
        const int m = id >> 6, ks = id & 63;
        const float* sp = S + (size_t)m * K_DIM + ks * 16;
        const float4 s0 = *(const float4*)(sp);
        const float4 s1 = *(const float4*)(sp + 4);
        const float4 s2 = *(const float4*)(sp + 8);
        const float4 s3 = *(const float4*)(sp + 12);
        const float sv[16] = {s0.x,s0.y,s0.z,s0.w, s1.x,s1.y,s1.z,s1.w,
                              s2.x,s2.y,s2.z,s2.w, s3.x,s3.y,s3.z,s3.w};
        union { signed char c[16]; int4v v; } u;
#pragma unroll
        for (int e = 0; e < 16; ++e) u.c[e] = (signed char)sv[e];   // exact 0/1
        const size_t off = ((size_t)(m >> 4) * 16 + (ks >> 2)) * 1024
                         + (size_t)((ks & 3) * 16 + (m & 15)) * 16;
        *(int4v*)(A8 + off) = u.v;
    } else if (bid < 1856) {
        // W -> 5 balanced base-256 digit planes, B-fragment order
        const int id = (bid - 1600) * 256 + threadIdx.x; // 0..65535
        const int n = id >> 6, ks = id & 63;
        const float* wp = W + (size_t)n * K_DIM + ks * 16;
        const float4 w0 = *(const float4*)(wp);
        const float4 w1 = *(const float4*)(wp + 4);
        const float4 w2 = *(const float4*)(wp + 8);
        const float4 w3 = *(const float4*)(wp + 12);
        const float wv[16] = {w0.x,w0.y,w0.z,w0.w, w1.x,w1.y,w1.z,w1.w,
                              w2.x,w2.y,w2.z,w2.w, w3.x,w3.y,w3.z,w3.w};
        union { signed char c[16]; int4v v; } u[5];
#pragma unroll
        for (int e = 0; e < 16; ++e) {
            long long q = llrint((double)wv[e] * 0x1p36);   // |q| < 2^39
#pragma unroll
            for (int p = 0; p < 4; ++p) {
                const int d = (int)(((q + 128) & 255) - 128);  // [-128,127]
                u[p].c[e] = (signed char)d;
                q = (q - d) >> 8;                              // exact
            }
            u[4].c[e] = (signed char)q;                        // |d4| <= ~90
        }
        const size_t base = ((size_t)(n >> 4) * 16 + (ks >> 2)) * 5 * 1024
                          + (size_t)((ks & 3) * 16 + (n & 15)) * 16;
#pragma unroll
        for (int p = 0; p < 5; ++p)
            *(int4v*)(Bt + base + (size_t)p * 1024) = u[p].v;
    } else {
        if (threadIdx.x < 32) colcnt[threadIdx.x] = 0;   // ws is poisoned 0xAA
    }
}

// ---- GEMM (R8 verbatim) + fused per-bn scan ----
__global__ __launch_bounds__(256)
void gemm_scan(const signed char* __restrict__ A8,
               const signed char* __restrict__ Bt,
               const float* __restrict__ bias,
               const float* __restrict__ mem0,
               float* __restrict__ out,          // du-hi then spikes, in place
               _Float16* __restrict__ Lo,        // lo*4096 residual
               int* __restrict__ colcnt) {
    const int bn = blockIdx.x;                 // 0..31  (fastest: XCD locality)
    const int bm = blockIdx.y;                 // 0..49
    const int tid = threadIdx.x;
    const int lane = tid & 63, wid = tid >> 6;
    const int wm = wid >> 1, wn = wid & 1;
    const int quad = lane >> 4, r16 = lane & 15;
    const int mgb = bm * 8 + wm * 4;
    const int ng  = bn * 2 + wn;

    const signed char* Ab = A8 + (size_t)mgb * 16384 + (size_t)lane * 16;
    const signed char* Bb = Bt + (size_t)ng * 81920 + (size_t)lane * 16;

    int4v a0[4], a1[4], b0[5], b1[5];
    int4v acc[4][5] = {};

    auto loadA = [&](int kt, int4v* a) {
#pragma unroll
        for (int i = 0; i < 4; ++i)
            a[i] = *(const int4v*)(Ab + (size_t)(i * 16 + kt) * 1024);
    };
    auto loadB = [&](int kt, int4v* b) {
#pragma unroll
        for (int p = 0; p < 5; ++p)
            b[p] = *(const int4v*)(Bb + (size_t)(kt * 5 + p) * 1024);
    };
    auto mf = [&](const int4v* a, const int4v* b) {
#pragma unroll
        for (int p = 0; p < 5; ++p)
#pragma unroll
            for (int i = 0; i < 4; ++i)
                acc[i][p] = __builtin_amdgcn_mfma_i32_16x16x64_i8(
                    a[i], b[p], acc[i][p], 0, 0, 0);
    };

    loadA(0, a0); loadB(0, b0);
    loadA(1, a1); loadB(1, b1);
    for (int kt = 0; kt < 16; kt += 2) {
        mf(a0, b0);
        if (kt + 2 < 16) { loadA(kt + 2, a0); loadB(kt + 2, b0); }
        mf(a1, b1);
        if (kt + 3 < 16) { loadA(kt + 3, a1); loadB(kt + 3, b1); }
    }

    // epilogue: exact i64 Horner recombine -> f64 du -> hi/lo store
    const int n_g = bn * 32 + wn * 16 + r16;
    const double bd = (double)bias[n_g];
#pragma unroll
    for (int i = 0; i < 4; ++i)
#pragma unroll
        for (int e = 0; e < 4; ++e) {
            long long t = (long long)acc[i][4][e];
            t = t * 256 + (long long)acc[i][3][e];
            t = t * 256 + (long long)acc[i][2][e];
            t = t * 256 + (long long)acc[i][1][e];
            t = t * 256 + (long long)acc[i][0][e];   // exact, |t| < 2^50
            const double du = (double)t * 0x1p-36 + bd;
            const float hi = (float)du;
            const float lo = (float)(du - (double)hi);
            const size_t m_g = (size_t)(bm * 128 + wm * 64 + i * 16 + quad * 4 + e);
            const size_t off = m_g * 1024 + n_g;
            out[off] = hi;
            Lo[off] = (_Float16)(lo * 4096.0f);
        }

    // ---- completion counter: release stores, claim scan if 50th ----
    __syncthreads();                 // all waves' stores vmcnt-drained
    __shared__ int s_old;
    if (tid == 0) {
        __threadfence();             // device-scope release (L2 writeback)
        s_old = atomicAdd(&colcnt[bn], 1);
    }
    __syncthreads();
    if (s_old != 49) return;
    __threadfence();                 // acquire: invalidate stale L1

    // ---- scan for this bn: 2048 chains, 8 per thread, f64 ----
    const int nl = tid & 31;                 // n within bn
    const int bb8 = (tid >> 5) << 3;         // first of 8 batches
    const size_t colb = (size_t)bb8 * 1024 + (size_t)bn * 32 + nl;

    double m[8], c[8];
    float h[2][8], l[2][8];
#pragma unroll
    for (int j = 0; j < 8; ++j) {
        m[j] = (double)mem0[colb + (size_t)j * 1024];
        c[j] = 0.0;
        h[0][j] = out[colb + (size_t)j * 1024];          // t=0
        l[0][j] = (float)Lo[colb + (size_t)j * 1024];
    }
    for (int t = 0; t < T_STEPS; ++t) {
        const int cur = t & 1, nxt = cur ^ 1;
        if (t + 1 < T_STEPS) {
#pragma unroll
            for (int j = 0; j < 8; ++j) {
                const size_t idx = (size_t)(t + 1) * BO + colb + (size_t)j * 1024;
                h[nxt][j] = out[idx];
                l[nxt][j] = (float)Lo[idx];
            }
        }
#pragma unroll
        for (int j = 0; j < 8; ++j) {
            const double du = (double)h[cur][j] + (double)l[cur][j] * 0x1p-12;
            m[j] += du;
            const double s = (m[j] > 15.0) ? 1.0 : 0.0;
            m[j] = fmin(fmax(m[j], 0.0), 15.0);
            out[(size_t)t * BO + colb + (size_t)j * 1024] = (float)s;
            c[j] += s;
            m[j] -= m[j] * s;
        }
    }
#pragma unroll
    for (int j = 0; j < 8; ++j) {
        out[(size_t)T_STEPS * BO + colb + (size_t)j * 1024] = (float)m[j];
        out[(size_t)(T_STEPS + 1) * BO + colb + (size_t)j * 1024]
            = (float)(c[j] * 0.01);
    }
}

extern "C" void kernel_launch(void* const* d_in, const int* in_sizes, int n_in,
                              void* d_out, int out_size, void* d_ws, size_t ws_size,
                              hipStream_t stream) {
    const float* spikes = (const float*)d_in[0];  // [100,64,1024]
    const float* mem    = (const float*)d_in[1];  // [64,1024]
    // d_in[2] = hat_spikes: dead in forward
    const float* W      = (const float*)d_in[3];  // [1024,1024]
    const float* b      = (const float*)d_in[4];  // [1024]
    float* out = (float*)d_out;
    signed char* A8 = (signed char*)d_ws + A8_OFF;
    signed char* Bt = (signed char*)d_ws + BT_OFF;
    _Float16*    Lo = (_Float16*)((char*)d_ws + LO_OFF);
    int*         colcnt = (int*)((char*)d_ws + CNT_OFF);

    prepass<<<dim3(1857), 256, 0, stream>>>(spikes, W, A8, Bt, colcnt);
    gemm_scan<<<dim3(32, 50), 256, 0, stream>>>(A8, Bt, b, mem, out, Lo, colcnt);
}

// Round 11
// 152.969 us; speedup vs baseline: 3.4386x; 3.4386x over previous
//
#include <hip/hip_runtime.h>

// SNNLinear, exact-trajectory i8-digit MFMA. Round 11 = R8 (proven 153us)
// with ONE change: GEMM block-id swizzle so co-resident blocks on a CU
// share bn (same B stream -> L1 temporal reuse; per-CU L2 demand drops
// from ~93 B/cyc to ~41 B/cyc, below the ~56 B/cyc port).
//   bid -> xcd=bid&7, t=bid>>3, cu=t&31, rnd=t>>5
//   bn = (xcd<<2)|(cu&3)   (4 B-chunks per XCD, L2-resident)
//   bm = (cu>>2)+(rnd<<3)  (bijection onto 32x50, verified)
// Math proven R3-R10 (bit-identical): Wq=round(W*2^36), 5 balanced base-256
// i8 digit planes; mfma_i32_16x16x64_i8 exact; i64 Horner -> f64 du ->
// f32 hi (ss region) + f16 lo*2^12 (ws). Scan in f64.
// Outputs: ss[100,64,1024] | mem_out[64,1024] | hat_s[64,1024]
// ws: [0,6.55M) A8 ; [6.55M,11.8M) Bt ; [11.8M,24.9M) Lo

typedef __attribute__((ext_vector_type(4))) int int4v;

#define T_STEPS 100
#define BO 65536
#define K_DIM 1024
#define A8_OFF 0
#define BT_OFF 6553600
#define LO_OFF 11796480

// ---- merged prepass: spikes -> A8 fragments ; W -> Bt digit planes ----
__global__ __launch_bounds__(256)
void prepass(const float* __restrict__ S, const float* __restrict__ W,
             signed char* __restrict__ A8, signed char* __restrict__ Bt) {
    const int bid = blockIdx.x;
    if (bid < 1600) {
        // spikes f32 -> i8, A-fragment order
        const int id = bid * 256 + threadIdx.x;          // 0..409599
        const int m = id >> 6, ks = id & 63;
        const float* sp = S + (size_t)m * K_DIM + ks * 16;
        const float4 s0 = *(const float4*)(sp);
        const float4 s1 = *(const float4*)(sp + 4);
        const float4 s2 = *(const float4*)(sp + 8);
        const float4 s3 = *(const float4*)(sp + 12);
        const float sv[16] = {s0.x,s0.y,s0.z,s0.w, s1.x,s1.y,s1.z,s1.w,
                              s2.x,s2.y,s2.z,s2.w, s3.x,s3.y,s3.z,s3.w};
        union { signed char c[16]; int4v v; } u;
#pragma unroll
        for (int e = 0; e < 16; ++e) u.c[e] = (signed char)sv[e];   // exact 0/1
        const size_t off = ((size_t)(m >> 4) * 16 + (ks >> 2)) * 1024
                         + (size_t)((ks & 3) * 16 + (m & 15)) * 16;
        *(int4v*)(A8 + off) = u.v;
    } else {
        // W -> 5 balanced base-256 digit planes, B-fragment order
        const int id = (bid - 1600) * 256 + threadIdx.x; // 0..65535
        const int n = id >> 6, ks = id & 63;
        const float* wp = W + (size_t)n * K_DIM + ks * 16;
        const float4 w0 = *(const float4*)(wp);
        const float4 w1 = *(const float4*)(wp + 4);
        const float4 w2 = *(const float4*)(wp + 8);
        const float4 w3 = *(const float4*)(wp + 12);
        const float wv[16] = {w0.x,w0.y,w0.z,w0.w, w1.x,w1.y,w1.z,w1.w,
                              w2.x,w2.y,w2.z,w2.w, w3.x,w3.y,w3.z,w3.w};
        union { signed char c[16]; int4v v; } u[5];
#pragma unroll
        for (int e = 0; e < 16; ++e) {
            long long q = llrint((double)wv[e] * 0x1p36);   // |q| < 2^39
#pragma unroll
            for (int p = 0; p < 4; ++p) {
                const int d = (int)(((q + 128) & 255) - 128);  // [-128,127]
                u[p].c[e] = (signed char)d;
                q = (q - d) >> 8;                              // exact
            }
            u[4].c[e] = (signed char)q;                        // |d4| <= ~90
        }
        const size_t base = ((size_t)(n >> 4) * 16 + (ks >> 2)) * 5 * 1024
                          + (size_t)((ks & 3) * 16 + (n & 15)) * 16;
#pragma unroll
        for (int p = 0; p < 5; ++p)
            *(int4v*)(Bt + base + (size_t)p * 1024) = u[p].v;
    }
}

// ---- GEMM: block 128m x 32n = 4 waves (2m x 2n), wave 64m x 16n x 5 planes.
// No LDS, no barriers; A/B stream global->VGPR in fragment order.
// Flat grid + swizzle: co-resident blocks per CU share bn. ----
__global__ __launch_bounds__(256)
void gemm_i8(const signed char* __restrict__ A8,
             const signed char* __restrict__ Bt,
             const float* __restrict__ bias,
             float* __restrict__ Chi,          // hi -> ss region
             _Float16* __restrict__ Lo) {      // lo*4096 residual
    const int bid = blockIdx.x;                // 0..1599
    const int xcd = bid & 7;
    const int t_  = bid >> 3;                  // 0..199
    const int cu  = t_ & 31;
    const int rnd = t_ >> 5;                   // 0..6
    const int bn = (xcd << 2) | (cu & 3);      // 0..31, fixed per (xcd,cu)
    const int bm = (cu >> 2) + (rnd << 3);     // 0..49, bijective

    const int tid = threadIdx.x;
    const int lane = tid & 63, wid = tid >> 6;
    const int wm = wid >> 1, wn = wid & 1;
    const int quad = lane >> 4, r16 = lane & 15;
    const int mgb = bm * 8 + wm * 4;
    const int ng  = bn * 2 + wn;

    const signed char* Ab = A8 + (size_t)mgb * 16384 + (size_t)lane * 16;
    const signed char* Bb = Bt + (size_t)ng * 81920 + (size_t)lane * 16;

    int4v a0[4], a1[4], b0[5], b1[5];
    int4v acc[4][5] = {};

    auto loadA = [&](int kt, int4v* a) {
#pragma unroll
        for (int i = 0; i < 4; ++i)
            a[i] = *(const int4v*)(Ab + (size_t)(i * 16 + kt) * 1024);
    };
    auto loadB = [&](int kt, int4v* b) {
#pragma unroll
        for (int p = 0; p < 5; ++p)
            b[p] = *(const int4v*)(Bb + (size_t)(kt * 5 + p) * 1024);
    };
    auto mf = [&](const int4v* a, const int4v* b) {
#pragma unroll
        for (int p = 0; p < 5; ++p)
#pragma unroll
            for (int i = 0; i < 4; ++i)
                acc[i][p] = __builtin_amdgcn_mfma_i32_16x16x64_i8(
                    a[i], b[p], acc[i][p], 0, 0, 0);
    };

    loadA(0, a0); loadB(0, b0);
    loadA(1, a1); loadB(1, b1);
    for (int kt = 0; kt < 16; kt += 2) {
        mf(a0, b0);
        if (kt + 2 < 16) { loadA(kt + 2, a0); loadB(kt + 2, b0); }
        mf(a1, b1);
        if (kt + 3 < 16) { loadA(kt + 3, a1); loadB(kt + 3, b1); }
    }

    // epilogue: exact i64 Horner recombine -> f64 du -> hi/lo store
    const int n_g = bn * 32 + wn * 16 + r16;
    const double bd = (double)bias[n_g];
#pragma unroll
    for (int i = 0; i < 4; ++i)
#pragma unroll
        for (int e = 0; e < 4; ++e) {
            long long t = (long long)acc[i][4][e];
            t = t * 256 + (long long)acc[i][3][e];
            t = t * 256 + (long long)acc[i][2][e];
            t = t * 256 + (long long)acc[i][1][e];
            t = t * 256 + (long long)acc[i][0][e];   // exact, |t| < 2^50
            const double du = (double)t * 0x1p-36 + bd;
            const float hi = (float)du;
            const float lo = (float)(du - (double)hi);
            const size_t m_g = (size_t)(bm * 128 + wm * 64 + i * 16 + quad * 4 + e);
            const size_t off = m_g * 1024 + n_g;
            Chi[off] = hi;
            Lo[off] = (_Float16)(lo * 4096.0f);
        }
}

// ---- membrane scan, f64, in place; 3-slot rolling 2-group-ahead prefetch ----
__global__ __launch_bounds__(256)
void snn_scan(float* __restrict__ out, const _Float16* __restrict__ lo,
              const float* __restrict__ mem0) {
    const int bo = blockIdx.x * 256 + threadIdx.x;
    double m = (double)mem0[bo];
    double cnt = 0.0;
    float h[3][4], l[3][4];
#pragma unroll
    for (int s = 0; s < 2; ++s)
#pragma unroll
        for (int u = 0; u < 4; ++u) {
            const size_t idx = (size_t)(s * 4 + u) * BO + bo;
            h[s][u] = out[idx];
            l[s][u] = (float)lo[idx];
        }
#pragma unroll
    for (int g = 0; g < 25; ++g) {
        const int cs = g % 3, ps = (g + 2) % 3;
        if (g + 2 < 25) {
#pragma unroll
            for (int u = 0; u < 4; ++u) {
                const size_t idx = (size_t)((g + 2) * 4 + u) * BO + bo;
                h[ps][u] = out[idx];
                l[ps][u] = (float)lo[idx];
            }
        }
#pragma unroll
        for (int u = 0; u < 4; ++u) {
            const double du = (double)h[cs][u] + (double)l[cs][u] * 0x1p-12;
            m += du;
            const double s = (m > 15.0) ? 1.0 : 0.0;
            m = fmin(fmax(m, 0.0), 15.0);
            out[(size_t)(g * 4 + u) * BO + bo] = (float)s;
            cnt += s;
            m -= m * s;
        }
    }
    out[(size_t)T_STEPS * BO + bo] = (float)m;
    out[(size_t)(T_STEPS + 1) * BO + bo] = (float)(cnt * 0.01);
}

extern "C" void kernel_launch(void* const* d_in, const int* in_sizes, int n_in,
                              void* d_out, int out_size, void* d_ws, size_t ws_size,
                              hipStream_t stream) {
    const float* spikes = (const float*)d_in[0];  // [100,64,1024]
    const float* mem    = (const float*)d_in[1];  // [64,1024]
    // d_in[2] = hat_spikes: dead in forward
    const float* W      = (const float*)d_in[3];  // [1024,1024]
    const float* b      = (const float*)d_in[4];  // [1024]
    float* out = (float*)d_out;
    signed char* A8 = (signed char*)d_ws + A8_OFF;
    signed char* Bt = (signed char*)d_ws + BT_OFF;
    _Float16*    Lo = (_Float16*)((char*)d_ws + LO_OFF);

    prepass<<<dim3(1856), 256, 0, stream>>>(spikes, W, A8, Bt);
    gemm_i8<<<dim3(1600), 256, 0, stream>>>(A8, Bt, b, out, Lo);
    snn_scan<<<dim3(BO / 256), 256, 0, stream>>>(out, Lo, mem);
}